// Round 12
// baseline (56.746 us; speedup 1.0000x reference)
//
#include <hip/hip_runtime.h>
#include <hip/hip_bf16.h>
#include <math.h>

#define H 128
#define NB 8
#define NVN 1024   // virtual nodes per batch
#define MLIG 64    // ligand atoms per batch
#define J 64       // H/2

typedef _Float16 f16;
typedef __attribute__((ext_vector_type(8))) _Float16 f16x8;
typedef __attribute__((ext_vector_type(4))) _Float16 f16x4;
typedef __attribute__((ext_vector_type(4))) float f32x4;

__device__ __forceinline__ f16x8 relu8(f16x8 x) {
    f16x8 z;
    #pragma unroll
    for (int i = 0; i < 8; ++i) z[i] = x[i] > (_Float16)0 ? x[i] : (_Float16)0;
    return z;
}

// DPP move (returns the lane-permuted value).
// 0xB1 = quad_perm xor1, 0x4E = quad_perm xor2,
// 0x124 = row_ror:4 (preserves c&3), 0x128 = row_ror:8.
template <int CTRL>
__device__ __forceinline__ float dpp_mov(float x) {
    union { float f; int i; } u, r;
    u.f = x;
    r.i = __builtin_amdgcn_update_dpp(0, u.i, CTRL, 0xf, 0xf, true);
    return r.f;
}

// -------------------------------------------------------------------------
// Kernel 0: repack W2 into MFMA B-fragment order:
//   W2p[(ks*4+fj)*64 + lane][e] = W2[(ks*32 + g*8 + e)*J + fj*16 + c]
// so pair threads load bw[ks][fj] as one coalesced 16B f16x8 each.
// -------------------------------------------------------------------------
__global__ __launch_bounds__(256) void repack_w2(
    const float* __restrict__ W2, f16* __restrict__ W2p)
{
    const int t    = blockIdx.x * 256 + threadIdx.x;   // 0..1023
    const int lane = t & 63;
    const int i    = t >> 6;                           // ks*4+fj
    const int ks   = i >> 2, fj = i & 3;
    const int g    = lane >> 4, c = lane & 15;

    f16x8 v;
    #pragma unroll
    for (int e = 0; e < 8; ++e)
        v[e] = (f16)W2[(ks * 32 + g * 8 + e) * J + fj * 16 + c];
    *(f16x8*)&W2p[(size_t)t * 8] = v;
}

// -------------------------------------------------------------------------
// Kernel 1: direct projection (no combine): v = (VE@Wv+bv)@W1v,
// l = (LE@Wl+bl)@W1l + b1. 16-row tiles, grid 544, f16 out. (R9, passed.)
// -------------------------------------------------------------------------
__global__ __launch_bounds__(256) void project_direct(
    const float* __restrict__ VE, const float* __restrict__ LE,
    const float* __restrict__ Wv, const float* __restrict__ bv,
    const float* __restrict__ Wl, const float* __restrict__ bl,
    const float* __restrict__ W1, const float* __restrict__ b1,
    f16* __restrict__ v_h, f16* __restrict__ l_h)
{
    __shared__ float Xs[16][132];
    __shared__ float Ts[16][132];
    const int bid = blockIdx.x;
    const int tid = threadIdx.x;

    const float* src; const float* Wa; const float* ba; const float* Wb;
    f16* dst; int r0; bool lig;
    if (bid < 512) { src = VE; Wa = Wv; ba = bv; Wb = W1 + H * H;
                     dst = v_h; r0 = bid * 16; lig = false; }
    else           { src = LE; Wa = Wl; ba = bl; Wb = W1;
                     dst = l_h; r0 = (bid - 512) * 16; lig = true; }

    #pragma unroll
    for (int i = 0; i < 2; ++i) {
        int s = tid + i * 256;
        int r = s >> 5, c4 = (s & 31) * 4;
        *(f32x4*)&Xs[r][c4] = *(const f32x4*)&src[(size_t)(r0 + r) * H + c4];
    }
    __syncthreads();

    const int rt = (tid >> 5) * 2;
    const int c0 = (tid & 31) * 4;

    f32x4 a0 = *(const f32x4*)&ba[c0];
    f32x4 a1 = a0;
    #pragma unroll 4
    for (int k4 = 0; k4 < 32; ++k4) {
        f32x4 x0 = *(const f32x4*)&Xs[rt][k4 * 4];
        f32x4 x1 = *(const f32x4*)&Xs[rt + 1][k4 * 4];
        f32x4 w0 = *(const f32x4*)&Wa[(size_t)(k4 * 4 + 0) * H + c0];
        f32x4 w1 = *(const f32x4*)&Wa[(size_t)(k4 * 4 + 1) * H + c0];
        f32x4 w2 = *(const f32x4*)&Wa[(size_t)(k4 * 4 + 2) * H + c0];
        f32x4 w3 = *(const f32x4*)&Wa[(size_t)(k4 * 4 + 3) * H + c0];
        a0 += x0[0] * w0; a0 += x0[1] * w1; a0 += x0[2] * w2; a0 += x0[3] * w3;
        a1 += x1[0] * w0; a1 += x1[1] * w1; a1 += x1[2] * w2; a1 += x1[3] * w3;
    }
    *(f32x4*)&Ts[rt][c0]     = a0;
    *(f32x4*)&Ts[rt + 1][c0] = a1;
    __syncthreads();

    f32x4 b0;
    if (lig) b0 = *(const f32x4*)&b1[c0];
    else     b0 = (f32x4){0.f, 0.f, 0.f, 0.f};
    f32x4 b1a = b0;
    #pragma unroll 4
    for (int k4 = 0; k4 < 32; ++k4) {
        f32x4 x0 = *(const f32x4*)&Ts[rt][k4 * 4];
        f32x4 x1 = *(const f32x4*)&Ts[rt + 1][k4 * 4];
        f32x4 w0 = *(const f32x4*)&Wb[(size_t)(k4 * 4 + 0) * H + c0];
        f32x4 w1 = *(const f32x4*)&Wb[(size_t)(k4 * 4 + 1) * H + c0];
        f32x4 w2 = *(const f32x4*)&Wb[(size_t)(k4 * 4 + 2) * H + c0];
        f32x4 w3 = *(const f32x4*)&Wb[(size_t)(k4 * 4 + 3) * H + c0];
        b0  += x0[0] * w0; b0  += x0[1] * w1; b0  += x0[2] * w2; b0  += x0[3] * w3;
        b1a += x1[0] * w0; b1a += x1[1] * w1; b1a += x1[2] * w2; b1a += x1[3] * w3;
    }

    f16x4 h0, h1;
    #pragma unroll
    for (int i = 0; i < 4; ++i) { h0[i] = (f16)b0[i]; h1[i] = (f16)b1a[i]; }
    *(f16x4*)&dst[(size_t)(r0 + rt) * H + c0]     = h0;
    *(f16x4*)&dst[(size_t)(r0 + rt + 1) * H + c0] = h1;
}

// -------------------------------------------------------------------------
// Kernel 2: pairwise MLP -> z, direct-load, no LDS/barriers (R11 structure)
// with the VALU diet: coalesced repacked-W2 fragment loads, b2 folded into
// MFMA C-init, select+rotate distribute-reduce (lane c ends with z of row
// r=c&3 summed over all 16 cols; write at c<4 as before).
// -------------------------------------------------------------------------
__global__ __launch_bounds__(256) void pair_z_direct(
    const f16* __restrict__ v_h, const f16* __restrict__ l_h,
    const f16* __restrict__ W2p, const float* __restrict__ b2,
    const float* __restrict__ W3, float* __restrict__ zbuf)
{
    const int bid = blockIdx.x;
    const int bm  = (bid & 7) * 64 + (bid >> 3);   // XCD swizzle, bijective
    const int b   = bm >> 6;

    const int tid  = threadIdx.x;
    const int wl   = tid >> 6;         // wave 0..3 -> n-quarter
    const int lane = tid & 63;
    const int g    = lane >> 4;
    const int c    = lane & 15;

    // W2 fragments: 16 coalesced 16B loads (repacked layout)
    f16x8 bw[4][4];
    #pragma unroll
    for (int ks = 0; ks < 4; ++ks)
        #pragma unroll
        for (int fj = 0; fj < 4; ++fj)
            bw[ks][fj] = *(const f16x8*)&W2p[(size_t)(((ks * 4 + fj) * 64) + lane) * 8];

    f16x8 lp[4];
    #pragma unroll
    for (int ks = 0; ks < 4; ++ks)
        lp[ks] = *(const f16x8*)&l_h[(size_t)bm * H + ks * 32 + g * 8];

    float b2r[4], w3r[4];
    #pragma unroll
    for (int fj = 0; fj < 4; ++fj) {
        b2r[fj] = b2[fj * 16 + c];
        w3r[fj] = W3[fj * 16 + c];
    }

    const bool sel1 = (c & 1) != 0;
    const bool sel2 = (c & 2) != 0;

    // lane's A-row base: row = b*NVN + wl*256 + c (+ f*16 per fragment)
    const f16* vbase = v_h + ((size_t)b * NVN + wl * 256 + c) * H + g * 8;
    float* zdst = zbuf + (size_t)bm * NVN + wl * 256;

    f16x8 cur[4], nxt[4];
    #pragma unroll
    for (int ks = 0; ks < 4; ++ks)
        cur[ks] = *(const f16x8*)(vbase + ks * 32);

    #pragma unroll 2
    for (int f = 0; f < 16; ++f) {
        if (f < 15) {                   // issue next fragment's loads early
            const f16* p = vbase + (size_t)(f + 1) * 16 * H;
            #pragma unroll
            for (int ks = 0; ks < 4; ++ks)
                nxt[ks] = *(const f16x8*)(p + ks * 32);
        }

        // b2 folded into accumulator init (saves the +b2 in layer 3)
        f32x4 acc[4];
        #pragma unroll
        for (int fj = 0; fj < 4; ++fj)
            acc[fj] = (f32x4){b2r[fj], b2r[fj], b2r[fj], b2r[fj]};

        #pragma unroll
        for (int ks = 0; ks < 4; ++ks) {
            f16x8 af = relu8(cur[ks] + lp[ks]);
            #pragma unroll
            for (int fj = 0; fj < 4; ++fj)
                acc[fj] = __builtin_amdgcn_mfma_f32_16x16x32_f16(
                    af, bw[ks][fj], acc[fj], 0, 0, 0);
        }

        // layer 3: pz[r] = sum_fj relu(acc[fj][r]) * w3r[fj]
        float pz[4];
        #pragma unroll
        for (int r = 0; r < 4; ++r)
            pz[r] = fmaxf(acc[0][r], 0.f) * w3r[0]
                  + fmaxf(acc[1][r], 0.f) * w3r[1]
                  + fmaxf(acc[2][r], 0.f) * w3r[2]
                  + fmaxf(acc[3][r], 0.f) * w3r[3];

        // distribute-reduce over the 16 c-lanes:
        // stage 1 (xor1, select r by c&1), stage 2 (xor2, select by c&2),
        // stages 3-4 (row_ror:4/8 — rotation preserves c&3).
        float t01 = sel1 ? pz[1] : pz[0];
        float u01 = sel1 ? pz[0] : pz[1];
        t01 += dpp_mov<0xB1>(u01);
        float t23 = sel1 ? pz[3] : pz[2];
        float u23 = sel1 ? pz[2] : pz[3];
        t23 += dpp_mov<0xB1>(u23);

        float tz = sel2 ? t23 : t01;
        float uz = sel2 ? t01 : t23;
        tz += dpp_mov<0x4E>(uz);

        tz += dpp_mov<0x124>(tz);   // row_ror:4
        tz += dpp_mov<0x128>(tz);   // row_ror:8

        if (c < 4)
            zdst[f * 16 + g * 4 + c] = tz;   // r = c

        #pragma unroll
        for (int ks = 0; ks < 4; ++ks) cur[ks] = nxt[ks];
    }
}

// -------------------------------------------------------------------------
// Kernel 3: per-(b,m) softmax over z + attn write + coords einsum.
// -------------------------------------------------------------------------
__global__ __launch_bounds__(256) void softmax_coords(
    const float* __restrict__ zbuf, const float* __restrict__ vc,
    float* __restrict__ out_coords, float* __restrict__ out_attn)
{
    __shared__ float red[4];
    __shared__ float redc[3][4];

    const int tid = threadIdx.x;
    const int bm  = blockIdx.x;
    const int b   = bm >> 6;
    const int wid = tid >> 6, lane = tid & 63;

    float zloc[4];
    float mx = -INFINITY;
    #pragma unroll
    for (int k = 0; k < 4; ++k) {
        zloc[k] = zbuf[(size_t)bm * NVN + tid + k * 256];
        mx = fmaxf(mx, zloc[k]);
    }
    #pragma unroll
    for (int off = 32; off > 0; off >>= 1) mx = fmaxf(mx, __shfl_xor(mx, off));
    if (lane == 0) red[wid] = mx;
    __syncthreads();
    if (tid == 0)
        red[0] = fmaxf(fmaxf(red[0], red[1]), fmaxf(red[2], red[3]));
    __syncthreads();
    const float gmax = red[0];
    __syncthreads();

    float s = 0.f;
    #pragma unroll
    for (int k = 0; k < 4; ++k) {
        zloc[k] = expf(zloc[k] - gmax);
        s += zloc[k];
    }
    #pragma unroll
    for (int off = 32; off > 0; off >>= 1) s += __shfl_xor(s, off);
    if (lane == 0) red[wid] = s;
    __syncthreads();
    if (tid == 0) red[0] = red[0] + red[1] + red[2] + red[3];
    __syncthreads();
    const float inv = 1.f / red[0];

    float cx = 0.f, cy = 0.f, cz = 0.f;
    #pragma unroll
    for (int k = 0; k < 4; ++k) {
        int n = tid + k * 256;
        float a = zloc[k] * inv;
        out_attn[(size_t)bm * NVN + n] = a;
        const float* vcp = vc + (size_t)(b * NVN + n) * 3;
        cx += a * vcp[0];
        cy += a * vcp[1];
        cz += a * vcp[2];
    }
    #pragma unroll
    for (int off = 32; off > 0; off >>= 1) {
        cx += __shfl_xor(cx, off);
        cy += __shfl_xor(cy, off);
        cz += __shfl_xor(cz, off);
    }
    if (lane == 0) { redc[0][wid] = cx; redc[1][wid] = cy; redc[2][wid] = cz; }
    __syncthreads();
    if (tid == 0) {
        out_coords[bm * 3 + 0] = redc[0][0] + redc[0][1] + redc[0][2] + redc[0][3];
        out_coords[bm * 3 + 1] = redc[1][0] + redc[1][1] + redc[1][2] + redc[1][3];
        out_coords[bm * 3 + 2] = redc[2][0] + redc[2][1] + redc[2][2] + redc[2][3];
    }
}

// -------------------------------------------------------------------------
extern "C" void kernel_launch(void* const* d_in, const int* in_sizes, int n_in,
                              void* d_out, int out_size, void* d_ws, size_t ws_size,
                              hipStream_t stream)
{
    const float* VE = (const float*)d_in[0];   // [8192, 128]
    const float* vc = (const float*)d_in[1];   // [8192, 3]
    const float* LE = (const float*)d_in[2];   // [512, 128]
    const float* Wv = (const float*)d_in[6];
    const float* bv = (const float*)d_in[7];
    const float* Wl = (const float*)d_in[8];
    const float* bl = (const float*)d_in[9];
    const float* W1 = (const float*)d_in[10];
    const float* b1 = (const float*)d_in[11];
    const float* W2 = (const float*)d_in[12];
    const float* b2 = (const float*)d_in[13];
    const float* W3 = (const float*)d_in[14];
    // b3 cancels in softmax

    float* ws   = (float*)d_ws;
    f16*   v_hp = (f16*)ws;                        // 8192*128 f16 = 2 MB
    f16*   l_hp = v_hp + (size_t)NB * NVN * H;     // 512*128 f16
    float* zbuf = (float*)(l_hp + (size_t)NB * MLIG * H);  // 512*1024 fp32
    f16*   W2p  = (f16*)(zbuf + (size_t)NB * MLIG * NVN);  // 16 KB

    float* out_coords = (float*)d_out;             // [512, 3]
    float* out_attn   = out_coords + NB * MLIG * 3;

    repack_w2<<<4, 256, 0, stream>>>(W2, W2p);

    project_direct<<<544, 256, 0, stream>>>(
        VE, LE, Wv, bv, Wl, bl, W1, b1, v_hp, l_hp);

    pair_z_direct<<<512, 256, 0, stream>>>(
        v_hp, l_hp, W2p, b2, W3, zbuf);

    softmax_coords<<<NB * MLIG, 256, 0, stream>>>(
        zbuf, vc, out_coords, out_attn);
}

// Round 13
// 49.203 us; speedup vs baseline: 1.1533x; 1.1533x over previous
//
#include <hip/hip_runtime.h>
#include <hip/hip_bf16.h>
#include <math.h>

#define H 128
#define NB 8
#define NVN 1024   // virtual nodes per batch
#define MLIG 64    // ligand atoms per batch
#define J 64       // H/2

typedef _Float16 f16;
typedef __attribute__((ext_vector_type(8))) _Float16 f16x8;
typedef __attribute__((ext_vector_type(4))) _Float16 f16x4;
typedef __attribute__((ext_vector_type(4))) float f32x4;

// relu(a+b) with guaranteed packed lowering: vector add -> v_pk_add_f16,
// __builtin_elementwise_max -> v_pk_max_f16 (no per-element cmp/cndmask).
__device__ __forceinline__ f16x8 addrelu8(f16x8 a, f16x8 b) {
    f16x8 s = a + b;
    const f16x8 z = {(_Float16)0, (_Float16)0, (_Float16)0, (_Float16)0,
                     (_Float16)0, (_Float16)0, (_Float16)0, (_Float16)0};
    return __builtin_elementwise_max(s, z);
}

template <int CTRL>
__device__ __forceinline__ float dpp_add(float x) {
    union { float f; int i; } u, r;
    u.f = x;
    r.i = __builtin_amdgcn_update_dpp(0, u.i, CTRL, 0xf, 0xf, true);
    return x + r.f;
}
__device__ __forceinline__ float row16_sum(float x) {
    x = dpp_add<0xB1>(x);   // xor 1
    x = dpp_add<0x4E>(x);   // xor 2
    x = dpp_add<0x141>(x);  // xor 4 (row_half_mirror)
    x = dpp_add<0x140>(x);  // xor 8 (row_mirror)
    return x;
}

// -------------------------------------------------------------------------
// Kernel 1: direct projection (no combine): v = (VE@Wv+bv)@W1v,
// l = (LE@Wl+bl)@W1l + b1. 16-row tiles, grid 544, f16 out. (R9, proven.)
// -------------------------------------------------------------------------
__global__ __launch_bounds__(256) void project_direct(
    const float* __restrict__ VE, const float* __restrict__ LE,
    const float* __restrict__ Wv, const float* __restrict__ bv,
    const float* __restrict__ Wl, const float* __restrict__ bl,
    const float* __restrict__ W1, const float* __restrict__ b1,
    f16* __restrict__ v_h, f16* __restrict__ l_h)
{
    __shared__ float Xs[16][132];
    __shared__ float Ts[16][132];
    const int bid = blockIdx.x;
    const int tid = threadIdx.x;

    const float* src; const float* Wa; const float* ba; const float* Wb;
    f16* dst; int r0; bool lig;
    if (bid < 512) { src = VE; Wa = Wv; ba = bv; Wb = W1 + H * H;
                     dst = v_h; r0 = bid * 16; lig = false; }
    else           { src = LE; Wa = Wl; ba = bl; Wb = W1;
                     dst = l_h; r0 = (bid - 512) * 16; lig = true; }

    #pragma unroll
    for (int i = 0; i < 2; ++i) {
        int s = tid + i * 256;
        int r = s >> 5, c4 = (s & 31) * 4;
        *(f32x4*)&Xs[r][c4] = *(const f32x4*)&src[(size_t)(r0 + r) * H + c4];
    }
    __syncthreads();

    const int rt = (tid >> 5) * 2;
    const int c0 = (tid & 31) * 4;

    f32x4 a0 = *(const f32x4*)&ba[c0];
    f32x4 a1 = a0;
    #pragma unroll 4
    for (int k4 = 0; k4 < 32; ++k4) {
        f32x4 x0 = *(const f32x4*)&Xs[rt][k4 * 4];
        f32x4 x1 = *(const f32x4*)&Xs[rt + 1][k4 * 4];
        f32x4 w0 = *(const f32x4*)&Wa[(size_t)(k4 * 4 + 0) * H + c0];
        f32x4 w1 = *(const f32x4*)&Wa[(size_t)(k4 * 4 + 1) * H + c0];
        f32x4 w2 = *(const f32x4*)&Wa[(size_t)(k4 * 4 + 2) * H + c0];
        f32x4 w3 = *(const f32x4*)&Wa[(size_t)(k4 * 4 + 3) * H + c0];
        a0 += x0[0] * w0; a0 += x0[1] * w1; a0 += x0[2] * w2; a0 += x0[3] * w3;
        a1 += x1[0] * w0; a1 += x1[1] * w1; a1 += x1[2] * w2; a1 += x1[3] * w3;
    }
    *(f32x4*)&Ts[rt][c0]     = a0;
    *(f32x4*)&Ts[rt + 1][c0] = a1;
    __syncthreads();

    f32x4 b0;
    if (lig) b0 = *(const f32x4*)&b1[c0];
    else     b0 = (f32x4){0.f, 0.f, 0.f, 0.f};
    f32x4 b1a = b0;
    #pragma unroll 4
    for (int k4 = 0; k4 < 32; ++k4) {
        f32x4 x0 = *(const f32x4*)&Ts[rt][k4 * 4];
        f32x4 x1 = *(const f32x4*)&Ts[rt + 1][k4 * 4];
        f32x4 w0 = *(const f32x4*)&Wb[(size_t)(k4 * 4 + 0) * H + c0];
        f32x4 w1 = *(const f32x4*)&Wb[(size_t)(k4 * 4 + 1) * H + c0];
        f32x4 w2 = *(const f32x4*)&Wb[(size_t)(k4 * 4 + 2) * H + c0];
        f32x4 w3 = *(const f32x4*)&Wb[(size_t)(k4 * 4 + 3) * H + c0];
        b0  += x0[0] * w0; b0  += x0[1] * w1; b0  += x0[2] * w2; b0  += x0[3] * w3;
        b1a += x1[0] * w0; b1a += x1[1] * w1; b1a += x1[2] * w2; b1a += x1[3] * w3;
    }

    f16x4 h0, h1;
    #pragma unroll
    for (int i = 0; i < 4; ++i) { h0[i] = (f16)b0[i]; h1[i] = (f16)b1a[i]; }
    *(f16x4*)&dst[(size_t)(r0 + rt) * H + c0]     = h0;
    *(f16x4*)&dst[(size_t)(r0 + rt + 1) * H + c0] = h1;
}

// -------------------------------------------------------------------------
// Kernel 2: pairwise MLP + fused softmax + coords. R11 direct-load
// structure (no LDS staging, no in-loop barriers), with:
//  - packed relu (addrelu8)
//  - 2-deep ping-pong unroll (no cur=nxt register copies)
//  - z kept in LDS; block softmax + coords tail (block owns all 1024 n)
// Grid 512 (one bm per block, XCD-swizzled), 256 thr = 4 waves.
// -------------------------------------------------------------------------
__global__ __launch_bounds__(256) void pair_attn_d(
    const f16* __restrict__ v_h, const f16* __restrict__ l_h,
    const float* __restrict__ W2, const float* __restrict__ b2,
    const float* __restrict__ W3, const float* __restrict__ vc,
    float* __restrict__ out_coords, float* __restrict__ out_attn)
{
    __shared__ float zrow[NVN];
    __shared__ float red[4];
    __shared__ float redc[3][4];

    const int bid = blockIdx.x;
    const int bm  = (bid & 7) * 64 + (bid >> 3);   // XCD swizzle, bijective
    const int b   = bm >> 6;

    const int tid  = threadIdx.x;
    const int wl   = tid >> 6;         // wave 0..3 -> n-quarter
    const int lane = tid & 63;
    const int g    = lane >> 4;
    const int c    = lane & 15;

    // W2 as f16 B-fragments in registers (once per block)
    f16x8 bw[4][4];
    #pragma unroll
    for (int ks = 0; ks < 4; ++ks)
        #pragma unroll
        for (int fj = 0; fj < 4; ++fj) {
            f16x8 f;
            #pragma unroll
            for (int e = 0; e < 8; ++e)
                f[e] = (f16)W2[(ks * 32 + g * 8 + e) * J + fj * 16 + c];
            bw[ks][fj] = f;
        }

    f16x8 lp[4];
    #pragma unroll
    for (int ks = 0; ks < 4; ++ks)
        lp[ks] = *(const f16x8*)&l_h[(size_t)bm * H + ks * 32 + g * 8];

    float b2r[4], w3r[4];
    #pragma unroll
    for (int fj = 0; fj < 4; ++fj) {
        b2r[fj] = b2[fj * 16 + c];
        w3r[fj] = W3[fj * 16 + c];
    }

    // lane's A-row base: row = b*NVN + wl*256 + c (+ f*16 per fragment)
    const f16* vbase = v_h + ((size_t)b * NVN + wl * 256 + c) * H + g * 8;
    float* zq = zrow + wl * 256;

    f16x8 cur0[4], cur1[4];
    #pragma unroll
    for (int ks = 0; ks < 4; ++ks)
        cur0[ks] = *(const f16x8*)(vbase + ks * 32);

    #define FRAG_COMPUTE(CUR, F)                                             \
    {                                                                        \
        f32x4 acc[4];                                                        \
        _Pragma("unroll")                                                    \
        for (int fj = 0; fj < 4; ++fj) acc[fj] = (f32x4){0.f,0.f,0.f,0.f};   \
        _Pragma("unroll")                                                    \
        for (int ks = 0; ks < 4; ++ks) {                                     \
            f16x8 af = addrelu8(CUR[ks], lp[ks]);                            \
            _Pragma("unroll")                                                \
            for (int fj = 0; fj < 4; ++fj)                                   \
                acc[fj] = __builtin_amdgcn_mfma_f32_16x16x32_f16(            \
                    af, bw[ks][fj], acc[fj], 0, 0, 0);                       \
        }                                                                    \
        float pz[4];                                                         \
        _Pragma("unroll")                                                    \
        for (int r = 0; r < 4; ++r) {                                        \
            float s = fmaxf(acc[0][r] + b2r[0], 0.f) * w3r[0]                \
                    + fmaxf(acc[1][r] + b2r[1], 0.f) * w3r[1]                \
                    + fmaxf(acc[2][r] + b2r[2], 0.f) * w3r[2]                \
                    + fmaxf(acc[3][r] + b2r[3], 0.f) * w3r[3];               \
            pz[r] = row16_sum(s);                                            \
        }                                                                    \
        if (c < 4) {                                                         \
            float zv = (c == 0) ? pz[0] : (c == 1) ? pz[1]                   \
                     : (c == 2) ? pz[2] : pz[3];                             \
            zq[(F) * 16 + g * 4 + c] = zv;                                   \
        }                                                                    \
    }

    #pragma unroll 1
    for (int f = 0; f < 16; f += 2) {
        // prefetch frag f+1 into cur1, compute frag f from cur0
        if (f + 1 < 16) {
            const f16* p = vbase + (size_t)(f + 1) * 16 * H;
            #pragma unroll
            for (int ks = 0; ks < 4; ++ks)
                cur1[ks] = *(const f16x8*)(p + ks * 32);
        }
        FRAG_COMPUTE(cur0, f)

        // prefetch frag f+2 into cur0, compute frag f+1 from cur1
        if (f + 2 < 16) {
            const f16* p = vbase + (size_t)(f + 2) * 16 * H;
            #pragma unroll
            for (int ks = 0; ks < 4; ++ks)
                cur0[ks] = *(const f16x8*)(p + ks * 32);
        }
        FRAG_COMPUTE(cur1, f + 1)
    }
    #undef FRAG_COMPUTE

    __syncthreads();   // zrow complete across all 4 waves

    // ---- softmax over zrow[0..1023] (b3 cancels), 4 elems per thread
    float zloc[4];
    float mx = -INFINITY;
    #pragma unroll
    for (int k = 0; k < 4; ++k) {
        zloc[k] = zrow[tid + k * 256];
        mx = fmaxf(mx, zloc[k]);
    }
    #pragma unroll
    for (int off = 32; off > 0; off >>= 1) mx = fmaxf(mx, __shfl_xor(mx, off));
    if (lane == 0) red[wl] = mx;
    __syncthreads();
    if (tid == 0)
        red[0] = fmaxf(fmaxf(red[0], red[1]), fmaxf(red[2], red[3]));
    __syncthreads();
    const float gmax = red[0];
    __syncthreads();

    float s = 0.f;
    #pragma unroll
    for (int k = 0; k < 4; ++k) {
        zloc[k] = expf(zloc[k] - gmax);
        s += zloc[k];
    }
    #pragma unroll
    for (int off = 32; off > 0; off >>= 1) s += __shfl_xor(s, off);
    if (lane == 0) red[wl] = s;
    __syncthreads();
    if (tid == 0) red[0] = red[0] + red[1] + red[2] + red[3];
    __syncthreads();
    const float inv = 1.f / red[0];

    float cx = 0.f, cy = 0.f, cz = 0.f;
    #pragma unroll
    for (int k = 0; k < 4; ++k) {
        int n = tid + k * 256;
        float a = zloc[k] * inv;
        out_attn[(size_t)bm * NVN + n] = a;
        const float* vcp = vc + (size_t)(b * NVN + n) * 3;
        cx += a * vcp[0];
        cy += a * vcp[1];
        cz += a * vcp[2];
    }
    #pragma unroll
    for (int off = 32; off > 0; off >>= 1) {
        cx += __shfl_xor(cx, off);
        cy += __shfl_xor(cy, off);
        cz += __shfl_xor(cz, off);
    }
    if (lane == 0) { redc[0][wl] = cx; redc[1][wl] = cy; redc[2][wl] = cz; }
    __syncthreads();
    if (tid == 0) {
        out_coords[bm * 3 + 0] = redc[0][0] + redc[0][1] + redc[0][2] + redc[0][3];
        out_coords[bm * 3 + 1] = redc[1][0] + redc[1][1] + redc[1][2] + redc[1][3];
        out_coords[bm * 3 + 2] = redc[2][0] + redc[2][1] + redc[2][2] + redc[2][3];
    }
}

// -------------------------------------------------------------------------
extern "C" void kernel_launch(void* const* d_in, const int* in_sizes, int n_in,
                              void* d_out, int out_size, void* d_ws, size_t ws_size,
                              hipStream_t stream)
{
    const float* VE = (const float*)d_in[0];   // [8192, 128]
    const float* vc = (const float*)d_in[1];   // [8192, 3]
    const float* LE = (const float*)d_in[2];   // [512, 128]
    const float* Wv = (const float*)d_in[6];
    const float* bv = (const float*)d_in[7];
    const float* Wl = (const float*)d_in[8];
    const float* bl = (const float*)d_in[9];
    const float* W1 = (const float*)d_in[10];
    const float* b1 = (const float*)d_in[11];
    const float* W2 = (const float*)d_in[12];
    const float* b2 = (const float*)d_in[13];
    const float* W3 = (const float*)d_in[14];
    // b3 cancels in softmax

    float* ws   = (float*)d_ws;
    f16*   v_hp = (f16*)ws;                        // 8192*128 f16 = 2 MB
    f16*   l_hp = v_hp + (size_t)NB * NVN * H;     // 512*128 f16

    float* out_coords = (float*)d_out;             // [512, 3]
    float* out_attn   = out_coords + NB * MLIG * 3;

    project_direct<<<544, 256, 0, stream>>>(
        VE, LE, Wv, bv, Wl, bl, W1, b1, v_hp, l_hp);

    pair_attn_d<<<512, 256, 0, stream>>>(
        v_hp, l_hp, W2, b2, W3, vc, out_coords, out_attn);
}

// Round 14
// 47.835 us; speedup vs baseline: 1.1863x; 1.0286x over previous
//
#include <hip/hip_runtime.h>
#include <hip/hip_bf16.h>
#include <math.h>

#define H 128
#define NB 8
#define NVN 1024   // virtual nodes per batch
#define MLIG 64    // ligand atoms per batch
#define J 64       // H/2

typedef _Float16 f16;
typedef __attribute__((ext_vector_type(8))) _Float16 f16x8;
typedef __attribute__((ext_vector_type(4))) _Float16 f16x4;
typedef __attribute__((ext_vector_type(4))) float f32x4;

// relu(a+b) with guaranteed packed lowering (v_pk_add_f16 + v_pk_max_f16).
__device__ __forceinline__ f16x8 addrelu8(f16x8 a, f16x8 b) {
    f16x8 s = a + b;
    const f16x8 z = {(_Float16)0, (_Float16)0, (_Float16)0, (_Float16)0,
                     (_Float16)0, (_Float16)0, (_Float16)0, (_Float16)0};
    return __builtin_elementwise_max(s, z);
}

template <int CTRL>
__device__ __forceinline__ float dpp_add(float x) {
    union { float f; int i; } u, r;
    u.f = x;
    r.i = __builtin_amdgcn_update_dpp(0, u.i, CTRL, 0xf, 0xf, true);
    return x + r.f;
}
__device__ __forceinline__ float row16_sum(float x) {
    x = dpp_add<0xB1>(x);   // xor 1
    x = dpp_add<0x4E>(x);   // xor 2
    x = dpp_add<0x141>(x);  // xor 4 (row_half_mirror)
    x = dpp_add<0x140>(x);  // xor 8 (row_mirror)
    return x;
}

// -------------------------------------------------------------------------
// Kernel 1: direct projection (no combine): v = (VE@Wv+bv)@W1v,
// l = (LE@Wl+bl)@W1l + b1. 16-row tiles, grid 544, f16 out. (R9, proven.)
// -------------------------------------------------------------------------
__global__ __launch_bounds__(256) void project_direct(
    const float* __restrict__ VE, const float* __restrict__ LE,
    const float* __restrict__ Wv, const float* __restrict__ bv,
    const float* __restrict__ Wl, const float* __restrict__ bl,
    const float* __restrict__ W1, const float* __restrict__ b1,
    f16* __restrict__ v_h, f16* __restrict__ l_h)
{
    __shared__ float Xs[16][132];
    __shared__ float Ts[16][132];
    const int bid = blockIdx.x;
    const int tid = threadIdx.x;

    const float* src; const float* Wa; const float* ba; const float* Wb;
    f16* dst; int r0; bool lig;
    if (bid < 512) { src = VE; Wa = Wv; ba = bv; Wb = W1 + H * H;
                     dst = v_h; r0 = bid * 16; lig = false; }
    else           { src = LE; Wa = Wl; ba = bl; Wb = W1;
                     dst = l_h; r0 = (bid - 512) * 16; lig = true; }

    #pragma unroll
    for (int i = 0; i < 2; ++i) {
        int s = tid + i * 256;
        int r = s >> 5, c4 = (s & 31) * 4;
        *(f32x4*)&Xs[r][c4] = *(const f32x4*)&src[(size_t)(r0 + r) * H + c4];
    }
    __syncthreads();

    const int rt = (tid >> 5) * 2;
    const int c0 = (tid & 31) * 4;

    f32x4 a0 = *(const f32x4*)&ba[c0];
    f32x4 a1 = a0;
    #pragma unroll 4
    for (int k4 = 0; k4 < 32; ++k4) {
        f32x4 x0 = *(const f32x4*)&Xs[rt][k4 * 4];
        f32x4 x1 = *(const f32x4*)&Xs[rt + 1][k4 * 4];
        f32x4 w0 = *(const f32x4*)&Wa[(size_t)(k4 * 4 + 0) * H + c0];
        f32x4 w1 = *(const f32x4*)&Wa[(size_t)(k4 * 4 + 1) * H + c0];
        f32x4 w2 = *(const f32x4*)&Wa[(size_t)(k4 * 4 + 2) * H + c0];
        f32x4 w3 = *(const f32x4*)&Wa[(size_t)(k4 * 4 + 3) * H + c0];
        a0 += x0[0] * w0; a0 += x0[1] * w1; a0 += x0[2] * w2; a0 += x0[3] * w3;
        a1 += x1[0] * w0; a1 += x1[1] * w1; a1 += x1[2] * w2; a1 += x1[3] * w3;
    }
    *(f32x4*)&Ts[rt][c0]     = a0;
    *(f32x4*)&Ts[rt + 1][c0] = a1;
    __syncthreads();

    f32x4 b0;
    if (lig) b0 = *(const f32x4*)&b1[c0];
    else     b0 = (f32x4){0.f, 0.f, 0.f, 0.f};
    f32x4 b1a = b0;
    #pragma unroll 4
    for (int k4 = 0; k4 < 32; ++k4) {
        f32x4 x0 = *(const f32x4*)&Ts[rt][k4 * 4];
        f32x4 x1 = *(const f32x4*)&Ts[rt + 1][k4 * 4];
        f32x4 w0 = *(const f32x4*)&Wb[(size_t)(k4 * 4 + 0) * H + c0];
        f32x4 w1 = *(const f32x4*)&Wb[(size_t)(k4 * 4 + 1) * H + c0];
        f32x4 w2 = *(const f32x4*)&Wb[(size_t)(k4 * 4 + 2) * H + c0];
        f32x4 w3 = *(const f32x4*)&Wb[(size_t)(k4 * 4 + 3) * H + c0];
        b0  += x0[0] * w0; b0  += x0[1] * w1; b0  += x0[2] * w2; b0  += x0[3] * w3;
        b1a += x1[0] * w0; b1a += x1[1] * w1; b1a += x1[2] * w2; b1a += x1[3] * w3;
    }

    f16x4 h0, h1;
    #pragma unroll
    for (int i = 0; i < 4; ++i) { h0[i] = (f16)b0[i]; h1[i] = (f16)b1a[i]; }
    *(f16x4*)&dst[(size_t)(r0 + rt) * H + c0]     = h0;
    *(f16x4*)&dst[(size_t)(r0 + rt + 1) * H + c0] = h1;
}

// -------------------------------------------------------------------------
// Kernel 2: pairwise MLP -> z, M-TILED: block = (batch b, m-tile of 16,
// n-tile of 64). Wave wl holds its 16-row vp fragment in REGISTERS for the
// whole kernel (loaded once -> v_h L2 traffic /16 vs per-m re-read), loops
// 16 m's with ping-pong-prefetched lp fragments (one 64B broadcast line
// per ks). No LDS, no barriers. Grid 512 = 8b x 4mt x 16nt, XCD-swizzled.
// -------------------------------------------------------------------------
__global__ __launch_bounds__(256) void pair_z_mt(
    const f16* __restrict__ v_h, const f16* __restrict__ l_h,
    const float* __restrict__ W2, const float* __restrict__ b2,
    const float* __restrict__ W3, float* __restrict__ zbuf)
{
    const int bid  = blockIdx.x;
    const int b    = bid & 7;          // XCD owns batch b
    const int rest = bid >> 3;         // 0..63
    const int mt   = rest & 3;         // m-tile (16 m's)
    const int nt   = rest >> 2;        // n-tile (64 n's), 0..15

    const int tid  = threadIdx.x;
    const int wl   = tid >> 6;         // wave 0..3 -> 16-row n-stripe
    const int lane = tid & 63;
    const int g    = lane >> 4;
    const int c    = lane & 15;

    // W2 as f16 B-fragments in registers (once per block)
    f16x8 bw[4][4];
    #pragma unroll
    for (int ks = 0; ks < 4; ++ks)
        #pragma unroll
        for (int fj = 0; fj < 4; ++fj) {
            f16x8 f;
            #pragma unroll
            for (int e = 0; e < 8; ++e)
                f[e] = (f16)W2[(ks * 32 + g * 8 + e) * J + fj * 16 + c];
            bw[ks][fj] = f;
        }

    float b2r[4], w3r[4];
    #pragma unroll
    for (int fj = 0; fj < 4; ++fj) {
        b2r[fj] = b2[fj * 16 + c];
        w3r[fj] = W3[fj * 16 + c];
    }

    // vp fragment: row = b*NVN + nt*64 + wl*16 + c; held in regs all kernel
    const f16* vrow = v_h + ((size_t)b * NVN + nt * 64 + wl * 16 + c) * H + g * 8;
    f16x8 cur[4];
    #pragma unroll
    for (int ks = 0; ks < 4; ++ks)
        cur[ks] = *(const f16x8*)(vrow + ks * 32);

    const int bm0 = b * 64 + mt * 16;
    const f16* lbase = l_h + (size_t)bm0 * H + g * 8;   // + mi*H per m
    float* zb = zbuf + (size_t)bm0 * NVN + nt * 64 + wl * 16;

    f16x8 lpA[4], lpB[4];
    #pragma unroll
    for (int ks = 0; ks < 4; ++ks)
        lpA[ks] = *(const f16x8*)(lbase + ks * 32);

    #define M_COMPUTE(LP, MI)                                                \
    {                                                                        \
        f32x4 acc[4];                                                        \
        _Pragma("unroll")                                                    \
        for (int fj = 0; fj < 4; ++fj) acc[fj] = (f32x4){0.f,0.f,0.f,0.f};   \
        _Pragma("unroll")                                                    \
        for (int ks = 0; ks < 4; ++ks) {                                     \
            f16x8 af = addrelu8(cur[ks], LP[ks]);                            \
            _Pragma("unroll")                                                \
            for (int fj = 0; fj < 4; ++fj)                                   \
                acc[fj] = __builtin_amdgcn_mfma_f32_16x16x32_f16(            \
                    af, bw[ks][fj], acc[fj], 0, 0, 0);                       \
        }                                                                    \
        float pz[4];                                                         \
        _Pragma("unroll")                                                    \
        for (int r = 0; r < 4; ++r) {                                        \
            float s = fmaxf(acc[0][r] + b2r[0], 0.f) * w3r[0]                \
                    + fmaxf(acc[1][r] + b2r[1], 0.f) * w3r[1]                \
                    + fmaxf(acc[2][r] + b2r[2], 0.f) * w3r[2]                \
                    + fmaxf(acc[3][r] + b2r[3], 0.f) * w3r[3];               \
            pz[r] = row16_sum(s);                                            \
        }                                                                    \
        if (c < 4) {                                                         \
            float zv = (c == 0) ? pz[0] : (c == 1) ? pz[1]                   \
                     : (c == 2) ? pz[2] : pz[3];                             \
            zb[(size_t)(MI) * NVN + g * 4 + c] = zv;                         \
        }                                                                    \
    }

    #pragma unroll 1
    for (int mi = 0; mi < 16; mi += 2) {
        // prefetch lp(mi+1) into lpB, compute mi from lpA
        if (mi + 1 < 16) {
            const f16* p = lbase + (size_t)(mi + 1) * H;
            #pragma unroll
            for (int ks = 0; ks < 4; ++ks)
                lpB[ks] = *(const f16x8*)(p + ks * 32);
        }
        M_COMPUTE(lpA, mi)

        // prefetch lp(mi+2) into lpA, compute mi+1 from lpB
        if (mi + 2 < 16) {
            const f16* p = lbase + (size_t)(mi + 2) * H;
            #pragma unroll
            for (int ks = 0; ks < 4; ++ks)
                lpA[ks] = *(const f16x8*)(p + ks * 32);
        }
        M_COMPUTE(lpB, mi + 1)
    }
    #undef M_COMPUTE
}

// -------------------------------------------------------------------------
// Kernel 3: per-(b,m) softmax over z + attn write + coords einsum. (proven)
// -------------------------------------------------------------------------
__global__ __launch_bounds__(256) void softmax_coords(
    const float* __restrict__ zbuf, const float* __restrict__ vc,
    float* __restrict__ out_coords, float* __restrict__ out_attn)
{
    __shared__ float red[4];
    __shared__ float redc[3][4];

    const int tid = threadIdx.x;
    const int bm  = blockIdx.x;
    const int b   = bm >> 6;
    const int wid = tid >> 6, lane = tid & 63;

    float zloc[4];
    float mx = -INFINITY;
    #pragma unroll
    for (int k = 0; k < 4; ++k) {
        zloc[k] = zbuf[(size_t)bm * NVN + tid + k * 256];
        mx = fmaxf(mx, zloc[k]);
    }
    #pragma unroll
    for (int off = 32; off > 0; off >>= 1) mx = fmaxf(mx, __shfl_xor(mx, off));
    if (lane == 0) red[wid] = mx;
    __syncthreads();
    if (tid == 0)
        red[0] = fmaxf(fmaxf(red[0], red[1]), fmaxf(red[2], red[3]));
    __syncthreads();
    const float gmax = red[0];
    __syncthreads();

    float s = 0.f;
    #pragma unroll
    for (int k = 0; k < 4; ++k) {
        zloc[k] = expf(zloc[k] - gmax);
        s += zloc[k];
    }
    #pragma unroll
    for (int off = 32; off > 0; off >>= 1) s += __shfl_xor(s, off);
    if (lane == 0) red[wid] = s;
    __syncthreads();
    if (tid == 0) red[0] = red[0] + red[1] + red[2] + red[3];
    __syncthreads();
    const float inv = 1.f / red[0];

    float cx = 0.f, cy = 0.f, cz = 0.f;
    #pragma unroll
    for (int k = 0; k < 4; ++k) {
        int n = tid + k * 256;
        float a = zloc[k] * inv;
        out_attn[(size_t)bm * NVN + n] = a;
        const float* vcp = vc + (size_t)(b * NVN + n) * 3;
        cx += a * vcp[0];
        cy += a * vcp[1];
        cz += a * vcp[2];
    }
    #pragma unroll
    for (int off = 32; off > 0; off >>= 1) {
        cx += __shfl_xor(cx, off);
        cy += __shfl_xor(cy, off);
        cz += __shfl_xor(cz, off);
    }
    if (lane == 0) { redc[0][wid] = cx; redc[1][wid] = cy; redc[2][wid] = cz; }
    __syncthreads();
    if (tid == 0) {
        out_coords[bm * 3 + 0] = redc[0][0] + redc[0][1] + redc[0][2] + redc[0][3];
        out_coords[bm * 3 + 1] = redc[1][0] + redc[1][1] + redc[1][2] + redc[1][3];
        out_coords[bm * 3 + 2] = redc[2][0] + redc[2][1] + redc[2][2] + redc[2][3];
    }
}

// -------------------------------------------------------------------------
extern "C" void kernel_launch(void* const* d_in, const int* in_sizes, int n_in,
                              void* d_out, int out_size, void* d_ws, size_t ws_size,
                              hipStream_t stream)
{
    const float* VE = (const float*)d_in[0];   // [8192, 128]
    const float* vc = (const float*)d_in[1];   // [8192, 3]
    const float* LE = (const float*)d_in[2];   // [512, 128]
    const float* Wv = (const float*)d_in[6];
    const float* bv = (const float*)d_in[7];
    const float* Wl = (const float*)d_in[8];
    const float* bl = (const float*)d_in[9];
    const float* W1 = (const float*)d_in[10];
    const float* b1 = (const float*)d_in[11];
    const float* W2 = (const float*)d_in[12];
    const float* b2 = (const float*)d_in[13];
    const float* W3 = (const float*)d_in[14];
    // b3 cancels in softmax

    float* ws   = (float*)d_ws;
    f16*   v_hp = (f16*)ws;                        // 8192*128 f16 = 2 MB
    f16*   l_hp = v_hp + (size_t)NB * NVN * H;     // 512*128 f16
    float* zbuf = (float*)(l_hp + (size_t)NB * MLIG * H);  // 512*1024 fp32

    float* out_coords = (float*)d_out;             // [512, 3]
    float* out_attn   = out_coords + NB * MLIG * 3;

    project_direct<<<544, 256, 0, stream>>>(
        VE, LE, Wv, bv, Wl, bl, W1, b1, v_hp, l_hp);

    pair_z_mt<<<512, 256, 0, stream>>>(
        v_hp, l_hp, W2, b2, W3, zbuf);

    softmax_coords<<<NB * MLIG, 256, 0, stream>>>(
        zbuf, vc, out_coords, out_attn);
}

// Round 15
// 34.797 us; speedup vs baseline: 1.6308x; 1.3747x over previous
//
#include <hip/hip_runtime.h>
#include <hip/hip_bf16.h>
#include <math.h>

#define H 128
#define NB 8
#define NVN 1024   // virtual nodes per batch
#define MLIG 64    // ligand atoms per batch
#define J 64       // H/2

typedef _Float16 f16;
typedef __attribute__((ext_vector_type(8))) _Float16 f16x8;
typedef __attribute__((ext_vector_type(4))) _Float16 f16x4;
typedef __attribute__((ext_vector_type(4))) float f32x4;

// relu(a+b) with guaranteed packed lowering (v_pk_add_f16 + v_pk_max_f16).
__device__ __forceinline__ f16x8 addrelu8(f16x8 a, f16x8 b) {
    f16x8 s = a + b;
    const f16x8 z = {(_Float16)0, (_Float16)0, (_Float16)0, (_Float16)0,
                     (_Float16)0, (_Float16)0, (_Float16)0, (_Float16)0};
    return __builtin_elementwise_max(s, z);
}

template <int CTRL>
__device__ __forceinline__ float dpp_add(float x) {
    union { float f; int i; } u, r;
    u.f = x;
    r.i = __builtin_amdgcn_update_dpp(0, u.i, CTRL, 0xf, 0xf, true);
    return x + r.f;
}
__device__ __forceinline__ float row16_sum(float x) {
    x = dpp_add<0xB1>(x);   // xor 1
    x = dpp_add<0x4E>(x);   // xor 2
    x = dpp_add<0x141>(x);  // xor 4 (row_half_mirror)
    x = dpp_add<0x140>(x);  // xor 8 (row_mirror)
    return x;
}

// -------------------------------------------------------------------------
// Kernel 1: fold projection layers (R6-proven structure, f16 Wc output).
//   Wc_v = Wv @ W1[H:], bias_v = bv @ W1[H:]
//   Wc_l = Wl @ W1[:H], bias_l = bl @ W1[:H] + b1
// -------------------------------------------------------------------------
__global__ __launch_bounds__(256) void combine_weights2(
    const float* __restrict__ Wv, const float* __restrict__ bv,
    const float* __restrict__ Wl, const float* __restrict__ bl,
    const float* __restrict__ W1, const float* __restrict__ b1,
    f16* __restrict__ Wc_v, f16* __restrict__ Wc_l,
    float* __restrict__ bias_v, float* __restrict__ bias_l)
{
    __shared__ float part[256];
    __shared__ float partb[256];
    const int tid = threadIdx.x;
    const int o   = tid & 127;
    const int kh  = tid >> 7;
    const int d   = blockIdx.x;
    const int mat = blockIdx.y;

    const float* Wsrc = (mat == 0) ? Wv : Wl;
    const float* W1p  = (mat == 0) ? (W1 + H * H) : W1;
    const float* bsrc = (mat == 0) ? bv : bl;
    f16* dst          = (mat == 0) ? Wc_v : Wc_l;

    float acc = 0.f, accb = 0.f;
    #pragma unroll 8
    for (int k = kh * 64; k < kh * 64 + 64; ++k) {
        float w = W1p[k * H + o];
        acc  += Wsrc[d * H + k] * w;
        accb += bsrc[k] * w;
    }
    part[tid]  = acc;
    partb[tid] = accb;
    __syncthreads();

    if (kh == 0) {
        dst[d * H + o] = (f16)(part[o] + part[o + 128]);
        if (d == 0) {
            float bb = partb[o] + partb[o + 128];
            if (mat == 0) bias_v[o] = bb;
            else          bias_l[o] = bb + b1[o];
        }
    }
}

// -------------------------------------------------------------------------
// Kernel 2: MFMA projection. Block = 16-row tile (grid 544), 256 thr =
// 4 waves; wave w covers j-range [w*32, w*32+32). X tile staged to LDS as
// f16 (XOR-swizzled, conflict-free b128 reads); B-frags from f16 Wc
// (scattered scalar loads, L2-resident, once per block). fp32 MFMA accum
// init = bias. Output f16 v_h / l_h.
// -------------------------------------------------------------------------
__global__ __launch_bounds__(256) void project_mfma(
    const float* __restrict__ VE, const float* __restrict__ LE,
    const f16* __restrict__ Wc_v, const f16* __restrict__ Wc_l,
    const float* __restrict__ bias_v, const float* __restrict__ bias_l,
    f16* __restrict__ v_h, f16* __restrict__ l_h)
{
    __shared__ f16 Xls[16 * 128];      // 4 KB
    const int bid = blockIdx.x;
    const int tid = threadIdx.x;

    const float* src; const f16* Wc; const float* bias; f16* dst; int r0;
    if (bid < 512) { src = VE; Wc = Wc_v; bias = bias_v; dst = v_h; r0 = bid * 16; }
    else           { src = LE; Wc = Wc_l; bias = bias_l; dst = l_h; r0 = (bid - 512) * 16; }

    // stage X tile: 16 rows x 128 f32 -> f16 LDS, chunk ^= row&7
    {
        const int r  = tid >> 4;       // 0..15
        const int k8 = tid & 15;       // 8-elem chunk
        const float* xs = src + (size_t)(r0 + r) * H + k8 * 8;
        f32x4 xa = *(const f32x4*)xs;
        f32x4 xb = *(const f32x4*)(xs + 4);
        f16x8 xh;
        #pragma unroll
        for (int i = 0; i < 4; ++i) { xh[i] = (f16)xa[i]; xh[4 + i] = (f16)xb[i]; }
        *(f16x8*)&Xls[r * 128 + (k8 ^ (r & 7)) * 8] = xh;
    }

    const int w    = tid >> 6;         // wave -> j-range
    const int lane = tid & 63;
    const int g    = lane >> 4;
    const int c    = lane & 15;

    // B-fragments for fj = 2w, 2w+1 (f16 scalar loads, pipelined)
    f16x8 bwf[4][2];
    #pragma unroll
    for (int ks = 0; ks < 4; ++ks)
        #pragma unroll
        for (int fj2 = 0; fj2 < 2; ++fj2) {
            f16x8 f;
            #pragma unroll
            for (int e = 0; e < 8; ++e)
                f[e] = Wc[(size_t)(ks * 32 + g * 8 + e) * H + (2 * w + fj2) * 16 + c];
            bwf[ks][fj2] = f;
        }

    f32x4 acc[2];
    #pragma unroll
    for (int fj2 = 0; fj2 < 2; ++fj2) {
        float bb = bias[(2 * w + fj2) * 16 + c];
        acc[fj2] = (f32x4){bb, bb, bb, bb};
    }
    __syncthreads();

    // A-fragments from LDS + MFMA
    #pragma unroll
    for (int ks = 0; ks < 4; ++ks) {
        f16x8 af = *(const f16x8*)&Xls[c * 128 + (((ks * 4 + g) ^ (c & 7)) * 8)];
        #pragma unroll
        for (int fj2 = 0; fj2 < 2; ++fj2)
            acc[fj2] = __builtin_amdgcn_mfma_f32_16x16x32_f16(
                af, bwf[ks][fj2], acc[fj2], 0, 0, 0);
    }

    // store D: row = g*4 + r, col = (2w+fj2)*16 + c
    #pragma unroll
    for (int fj2 = 0; fj2 < 2; ++fj2)
        #pragma unroll
        for (int r = 0; r < 4; ++r)
            dst[(size_t)(r0 + g * 4 + r) * H + (2 * w + fj2) * 16 + c] =
                (f16)acc[fj2][r];
}

// -------------------------------------------------------------------------
// Kernel 3: pairwise MLP -> z, m-tiled (R14 structure) at 4 blocks/CU:
// grid 1024 = 8b x 8mt x 16nt (m-tile of 8). Wave holds its 16-row vp
// fragment in regs; loops 8 m's with ping-pong lp prefetch. No LDS/barriers.
// -------------------------------------------------------------------------
__global__ __launch_bounds__(256) void pair_z_mt(
    const f16* __restrict__ v_h, const f16* __restrict__ l_h,
    const float* __restrict__ W2, const float* __restrict__ b2,
    const float* __restrict__ W3, float* __restrict__ zbuf)
{
    const int bid  = blockIdx.x;
    const int b    = bid & 7;          // XCD owns batch b
    const int rest = bid >> 3;         // 0..127
    const int mt   = rest & 7;         // m-tile (8 m's)
    const int nt   = rest >> 3;        // n-tile (64 n's), 0..15

    const int tid  = threadIdx.x;
    const int wl   = tid >> 6;         // wave 0..3 -> 16-row n-stripe
    const int lane = tid & 63;
    const int g    = lane >> 4;
    const int c    = lane & 15;

    // W2 as f16 B-fragments in registers (once per block)
    f16x8 bw[4][4];
    #pragma unroll
    for (int ks = 0; ks < 4; ++ks)
        #pragma unroll
        for (int fj = 0; fj < 4; ++fj) {
            f16x8 f;
            #pragma unroll
            for (int e = 0; e < 8; ++e)
                f[e] = (f16)W2[(ks * 32 + g * 8 + e) * J + fj * 16 + c];
            bw[ks][fj] = f;
        }

    float b2r[4], w3r[4];
    #pragma unroll
    for (int fj = 0; fj < 4; ++fj) {
        b2r[fj] = b2[fj * 16 + c];
        w3r[fj] = W3[fj * 16 + c];
    }

    // vp fragment: row = b*NVN + nt*64 + wl*16 + c; held in regs all kernel
    const f16* vrow = v_h + ((size_t)b * NVN + nt * 64 + wl * 16 + c) * H + g * 8;
    f16x8 cur[4];
    #pragma unroll
    for (int ks = 0; ks < 4; ++ks)
        cur[ks] = *(const f16x8*)(vrow + ks * 32);

    const int bm0 = b * 64 + mt * 8;
    const f16* lbase = l_h + (size_t)bm0 * H + g * 8;   // + mi*H per m
    float* zb = zbuf + (size_t)bm0 * NVN + nt * 64 + wl * 16;

    f16x8 lpA[4], lpB[4];
    #pragma unroll
    for (int ks = 0; ks < 4; ++ks)
        lpA[ks] = *(const f16x8*)(lbase + ks * 32);

    #define M_COMPUTE(LP, MI)                                                \
    {                                                                        \
        f32x4 acc[4];                                                        \
        _Pragma("unroll")                                                    \
        for (int fj = 0; fj < 4; ++fj) acc[fj] = (f32x4){0.f,0.f,0.f,0.f};   \
        _Pragma("unroll")                                                    \
        for (int ks = 0; ks < 4; ++ks) {                                     \
            f16x8 af = addrelu8(cur[ks], LP[ks]);                            \
            _Pragma("unroll")                                                \
            for (int fj = 0; fj < 4; ++fj)                                   \
                acc[fj] = __builtin_amdgcn_mfma_f32_16x16x32_f16(            \
                    af, bw[ks][fj], acc[fj], 0, 0, 0);                       \
        }                                                                    \
        float pz[4];                                                         \
        _Pragma("unroll")                                                    \
        for (int r = 0; r < 4; ++r) {                                        \
            float s = fmaxf(acc[0][r] + b2r[0], 0.f) * w3r[0]                \
                    + fmaxf(acc[1][r] + b2r[1], 0.f) * w3r[1]                \
                    + fmaxf(acc[2][r] + b2r[2], 0.f) * w3r[2]                \
                    + fmaxf(acc[3][r] + b2r[3], 0.f) * w3r[3];               \
            pz[r] = row16_sum(s);                                            \
        }                                                                    \
        if (c < 4) {                                                         \
            float zv = (c == 0) ? pz[0] : (c == 1) ? pz[1]                   \
                     : (c == 2) ? pz[2] : pz[3];                             \
            zb[(size_t)(MI) * NVN + g * 4 + c] = zv;                         \
        }                                                                    \
    }

    #pragma unroll 1
    for (int mi = 0; mi < 8; mi += 2) {
        if (mi + 1 < 8) {
            const f16* p = lbase + (size_t)(mi + 1) * H;
            #pragma unroll
            for (int ks = 0; ks < 4; ++ks)
                lpB[ks] = *(const f16x8*)(p + ks * 32);
        }
        M_COMPUTE(lpA, mi)

        if (mi + 2 < 8) {
            const f16* p = lbase + (size_t)(mi + 2) * H;
            #pragma unroll
            for (int ks = 0; ks < 4; ++ks)
                lpA[ks] = *(const f16x8*)(p + ks * 32);
        }
        M_COMPUTE(lpB, mi + 1)
    }
    #undef M_COMPUTE
}

// -------------------------------------------------------------------------
// Kernel 4: per-(b,m) softmax over z + attn write + coords einsum. (proven)
// -------------------------------------------------------------------------
__global__ __launch_bounds__(256) void softmax_coords(
    const float* __restrict__ zbuf, const float* __restrict__ vc,
    float* __restrict__ out_coords, float* __restrict__ out_attn)
{
    __shared__ float red[4];
    __shared__ float redc[3][4];

    const int tid = threadIdx.x;
    const int bm  = blockIdx.x;
    const int b   = bm >> 6;
    const int wid = tid >> 6, lane = tid & 63;

    float zloc[4];
    float mx = -INFINITY;
    #pragma unroll
    for (int k = 0; k < 4; ++k) {
        zloc[k] = zbuf[(size_t)bm * NVN + tid + k * 256];
        mx = fmaxf(mx, zloc[k]);
    }
    #pragma unroll
    for (int off = 32; off > 0; off >>= 1) mx = fmaxf(mx, __shfl_xor(mx, off));
    if (lane == 0) red[wid] = mx;
    __syncthreads();
    if (tid == 0)
        red[0] = fmaxf(fmaxf(red[0], red[1]), fmaxf(red[2], red[3]));
    __syncthreads();
    const float gmax = red[0];
    __syncthreads();

    float s = 0.f;
    #pragma unroll
    for (int k = 0; k < 4; ++k) {
        zloc[k] = expf(zloc[k] - gmax);
        s += zloc[k];
    }
    #pragma unroll
    for (int off = 32; off > 0; off >>= 1) s += __shfl_xor(s, off);
    if (lane == 0) red[wid] = s;
    __syncthreads();
    if (tid == 0) red[0] = red[0] + red[1] + red[2] + red[3];
    __syncthreads();
    const float inv = 1.f / red[0];

    float cx = 0.f, cy = 0.f, cz = 0.f;
    #pragma unroll
    for (int k = 0; k < 4; ++k) {
        int n = tid + k * 256;
        float a = zloc[k] * inv;
        out_attn[(size_t)bm * NVN + n] = a;
        const float* vcp = vc + (size_t)(b * NVN + n) * 3;
        cx += a * vcp[0];
        cy += a * vcp[1];
        cz += a * vcp[2];
    }
    #pragma unroll
    for (int off = 32; off > 0; off >>= 1) {
        cx += __shfl_xor(cx, off);
        cy += __shfl_xor(cy, off);
        cz += __shfl_xor(cz, off);
    }
    if (lane == 0) { redc[0][wid] = cx; redc[1][wid] = cy; redc[2][wid] = cz; }
    __syncthreads();
    if (tid == 0) {
        out_coords[bm * 3 + 0] = redc[0][0] + redc[0][1] + redc[0][2] + redc[0][3];
        out_coords[bm * 3 + 1] = redc[1][0] + redc[1][1] + redc[1][2] + redc[1][3];
        out_coords[bm * 3 + 2] = redc[2][0] + redc[2][1] + redc[2][2] + redc[2][3];
    }
}

// -------------------------------------------------------------------------
extern "C" void kernel_launch(void* const* d_in, const int* in_sizes, int n_in,
                              void* d_out, int out_size, void* d_ws, size_t ws_size,
                              hipStream_t stream)
{
    const float* VE = (const float*)d_in[0];   // [8192, 128]
    const float* vc = (const float*)d_in[1];   // [8192, 3]
    const float* LE = (const float*)d_in[2];   // [512, 128]
    const float* Wv = (const float*)d_in[6];
    const float* bv = (const float*)d_in[7];
    const float* Wl = (const float*)d_in[8];
    const float* bl = (const float*)d_in[9];
    const float* W1 = (const float*)d_in[10];
    const float* b1 = (const float*)d_in[11];
    const float* W2 = (const float*)d_in[12];
    const float* b2 = (const float*)d_in[13];
    const float* W3 = (const float*)d_in[14];
    // b3 cancels in softmax

    float* ws     = (float*)d_ws;
    f16*   Wc_vh  = (f16*)ws;                      // 16384 f16
    f16*   Wc_lh  = Wc_vh + H * H;                 // 16384 f16
    float* bias_v = ws + 16384;                    // 128 f32 (after 32768 f16)
    float* bias_l = bias_v + 128;
    f16*   v_hp   = (f16*)(bias_l + 128);          // 8192*128 f16
    f16*   l_hp   = v_hp + (size_t)NB * NVN * H;   // 512*128 f16
    float* zbuf   = (float*)(l_hp + (size_t)NB * MLIG * H);  // 512*1024 f32

    float* out_coords = (float*)d_out;             // [512, 3]
    float* out_attn   = out_coords + NB * MLIG * 3;

    combine_weights2<<<dim3(H, 2), 256, 0, stream>>>(
        Wv, bv, Wl, bl, W1, b1, Wc_vh, Wc_lh, bias_v, bias_l);

    project_mfma<<<544, 256, 0, stream>>>(
        VE, LE, Wc_vh, Wc_lh, bias_v, bias_l, v_hp, l_hp);

    pair_z_mt<<<1024, 256, 0, stream>>>(
        v_hp, l_hp, W2, b2, W3, zbuf);

    softmax_coords<<<NB * MLIG, 256, 0, stream>>>(
        zbuf, vc, out_coords, out_attn);
}